// Round 3
// baseline (484.947 us; speedup 1.0000x reference)
//
#include <hip/hip_runtime.h>
#include <hip/hip_bf16.h>
#include <math.h>

#define NN 8192
#define DD 128
#define EE 262144
#define CAPM 128

typedef __attribute__((ext_vector_type(8))) short bf16x8;
typedef __attribute__((ext_vector_type(4))) float f32x4;

// ---------------- init: deg=1 (self loop), cnt=0 (ws is poisoned each call) --
__global__ __launch_bounds__(256) void k_init(int* deg, int* cnt) {
  int i = blockIdx.x * 256 + threadIdx.x;
  if (i < NN) { deg[i] = 1; cnt[i] = 0; }
}

// ---------------- scatter edges: degree count + per-row col buckets ---------
__global__ __launch_bounds__(256) void k_scatter(const int* __restrict__ ei,
                                                 int* deg, int* cnt, int* bucket) {
  int e = blockIdx.x * 256 + threadIdx.x;
  if (e < EE) {
    int r = ei[e];
    int c = ei[EE + e];
    atomicAdd(&deg[c], 1);
    int pos = atomicAdd(&cnt[r], 1);
    if (pos < CAPM - 1) bucket[r * CAPM + pos] = c;   // reserve last slot for self-loop
  }
}

__global__ __launch_bounds__(256) void k_dinv(const int* __restrict__ deg, float* dinv) {
  int i = blockIdx.x * 256 + threadIdx.x;
  if (i < NN) dinv[i] = 1.0f / sqrtf((float)deg[i]);
}

// ---------------- h = x @ W (fp32, W rows L2-resident) ----------------------
__global__ __launch_bounds__(256) void k_linear(const float* __restrict__ x,
                                                const float* __restrict__ W,
                                                float* __restrict__ h) {
  __shared__ float xr[2][DD];
  int j = threadIdx.x & 127, par = threadIdx.x >> 7;
  for (int rr = 0; rr < 16; rr += 2) {
    int row = blockIdx.x * 16 + rr + par;
    __syncthreads();
    xr[par][j] = x[row * DD + j];
    __syncthreads();
    float acc = 0.f;
    #pragma unroll 8
    for (int k = 0; k < DD; k++) acc = fmaf(xr[par][k], W[k * DD + j], acc);
    h[row * DD + j] = acc;
  }
}

// ---------------- per-row soft-k-medoid + bias + relu -> bf16 o -------------
#define XS 132   // LDS row stride (floats): 16B-aligned, bank-staggered
__global__ __launch_bounds__(256) void k_medoid(const int* __restrict__ cnt,
                                                const int* __restrict__ bucket,
                                                const float* __restrict__ dinv,
                                                const float* __restrict__ h,
                                                const float* __restrict__ bias,
                                                __hip_bfloat16* __restrict__ obf) {
  __shared__ int   sc[CAPM];
  __shared__ float sdv[CAPM];
  __shared__ float uw[CAPM];
  __shared__ int   uc[CAPM];
  __shared__ float Xk[64 * XS];
  __shared__ float sq[64];
  __shared__ float lv[64];
  __shared__ float carr[64];
  __shared__ float red[4];
  __shared__ int   s_wcnt[4];
  __shared__ float s_rs;
  __shared__ int   s_mu;

  const int r = blockIdx.x;
  const int tid = threadIdx.x;
  const int lane = tid & 63, wid = tid >> 6;

  const int cntr = min(cnt[r], CAPM - 1);
  const int m = cntr + 1;                      // + self loop
  for (int p = tid; p < cntr; p += 256) sc[p] = bucket[r * CAPM + p];
  if (tid == 0) sc[cntr] = r;
  __syncthreads();
  const float dr = dinv[r];
  for (int p = tid; p < m; p += 256) sdv[p] = dinv[sc[p]];
  __syncthreads();

  // dedup: head flag + multiplicity (coalesce duplicate edges); O(m) per entry
  bool head = false; int mult = 0; int c = -1; float dvp = 0.f;
  if (tid < m) {
    c = sc[tid]; dvp = sdv[tid];
    head = true;
    for (int q = 0; q < m; q++) {
      int cq = sc[q];
      if (cq == c) { mult++; if (q < tid) head = false; }
    }
  }

  // row_sum = dr * sum over ALL entries (incl. duplicates, incl. beyond top-64)
  float rpart = (tid < m) ? dvp : 0.f;
  for (int o = 32; o; o >>= 1) rpart += __shfl_xor(rpart, o);
  if (lane == 0) red[wid] = rpart;
  __syncthreads();
  if (tid == 0) s_rs = dr * (red[0] + red[1] + red[2] + red[3]);

  // compact heads -> unique (col, weight) list
  unsigned long long bal = __ballot(head);
  int rank = __popcll(bal & ((1ULL << lane) - 1ULL));
  if (lane == 0) s_wcnt[wid] = __popcll(bal);
  __syncthreads();
  int ubase = 0;
  for (int wq = 0; wq < wid; wq++) ubase += s_wcnt[wq];
  if (head) { int u = ubase + rank; uc[u] = c; uw[u] = (float)mult * dr * dvp; }
  if (tid == 0) s_mu = s_wcnt[0] + s_wcnt[1] + s_wcnt[2] + s_wcnt[3];
  __syncthreads();
  const int mu = s_mu;
  const float rs = s_rs;

  // rare path: >64 distinct neighbors -> bitonic sort desc by (w, col asc), keep 64
  if (mu > 64) {
    for (int p = tid; p < CAPM; p += 256)
      if (p >= mu) { uw[p] = -1.f; uc[p] = 0x7fffffff; }
    __syncthreads();
    for (int kk = 2; kk <= CAPM; kk <<= 1) {
      for (int jj = kk >> 1; jj > 0; jj >>= 1) {
        if (tid < CAPM) {
          int ixj = tid ^ jj;
          if (ixj > tid) {
            float w1 = uw[tid], w2 = uw[ixj];
            int   c1 = uc[tid], c2 = uc[ixj];
            bool firstBefore = (w1 > w2) || (w1 == w2 && c1 < c2);
            bool up = ((tid & kk) == 0);
            bool sw = up ? !firstBefore : firstBefore;
            if (sw) { uw[tid] = w2; uw[ixj] = w1; uc[tid] = c2; uc[ixj] = c1; }
          }
        }
        __syncthreads();
      }
    }
  }
  __syncthreads();
  const int K = min(mu, 64);

  // gather neighborhood vectors h[uc[u]] into LDS
  for (int t = tid; t < K * 32; t += 256) {
    int u = t >> 5, d4 = t & 31;
    float4 v = *(const float4*)(h + (size_t)uc[u] * DD + d4 * 4);
    *(float4*)(Xk + u * XS + d4 * 4) = v;
  }
  __syncthreads();

  // squared norms
  {
    int u = tid >> 2, sub = tid & 3;
    if (u < 64) {
      float acc = 0.f;
      if (u < K) {
        for (int d4 = sub; d4 < 32; d4 += 4) {
          float4 v = *(const float4*)(Xk + u * XS + d4 * 4);
          acc += v.x * v.x + v.y * v.y + v.z * v.z + v.w * v.w;
        }
      }
      acc += __shfl_xor(acc, 1);
      acc += __shfl_xor(acc, 2);
      if (sub == 0 && u < K) sq[u] = acc;
    }
  }
  __syncthreads();

  // l_j = sum_m w_m * sqrt(max(sq_j + sq_m - 2<x_j,x_m>, 1e-12))
  {
    int j = tid >> 2, sub = tid & 3;
    float lacc = 0.f;
    if (j < K) {
      float sqj = sq[j];
      const float* A = Xk + j * XS;
      for (int mm = sub; mm < K; mm += 4) {
        const float* B = Xk + mm * XS;
        float dot = 0.f;
        #pragma unroll 8
        for (int d4 = 0; d4 < 32; d4++) {
          float4 a = *(const float4*)(A + d4 * 4);
          float4 bq = *(const float4*)(B + d4 * 4);
          dot = fmaf(a.x, bq.x, fmaf(a.y, bq.y, fmaf(a.z, bq.z, fmaf(a.w, bq.w, dot))));
        }
        float d2 = sqj + sq[mm] - 2.f * dot;
        float dist = sqrtf(fmaxf(d2, 1e-12f));
        lacc = fmaf(uw[mm], dist, lacc);
      }
    }
    lacc += __shfl_xor(lacc, 1);
    lacc += __shfl_xor(lacc, 2);
    if (j < K && (tid & 3) == 0) lv[j] = lacc;
  }
  __syncthreads();

  // softmax(-l/row_sum) * w, normalized, scaled by row_sum (single wave)
  if (tid < 64) {
    float lj = (tid < K) ? lv[tid] : INFINITY;
    float z = -lj / rs;
    float zm = z;
    for (int o = 32; o; o >>= 1) zm = fmaxf(zm, __shfl_xor(zm, o));
    float e = (tid < K) ? expf(z - zm) : 0.f;
    float esum = e;
    for (int o = 32; o; o >>= 1) esum += __shfl_xor(esum, o);
    float s = e / esum;
    float cc = (tid < K) ? s * uw[tid] : 0.f;
    float csum = cc;
    for (int o = 32; o; o >>= 1) csum += __shfl_xor(csum, o);
    carr[tid] = cc / csum * rs;
  }
  __syncthreads();

  // out_row = sum_j c_j * x_j ; + bias ; relu ; store bf16
  if (tid < DD) {
    int d = tid;
    float acc = 0.f;
    for (int j = 0; j < K; j++) acc = fmaf(carr[j], Xk[j * XS + d], acc);
    acc += bias[d];
    acc = fmaxf(acc, 0.f);
    obf[(size_t)r * DD + d] = __float2bfloat16(acc);
  }
}

// ---------------- C = o @ o^T  (bf16 MFMA, K=128, operands L2-resident) -----
__global__ __launch_bounds__(256) void k_outer(const short* __restrict__ ob,
                                               float* __restrict__ C) {
  const int lane = threadIdx.x & 63, w = threadIdx.x >> 6;
  const int R0 = blockIdx.x * 128 + (w >> 1) * 64;
  const int C0 = blockIdx.y * 128 + (w & 1) * 64;
  const int ra = lane & 15;
  const int kg = (lane >> 4) * 8;

  f32x4 acc[4][4] = {};
  #pragma unroll
  for (int ks = 0; ks < 4; ks++) {
    bf16x8 a[4], bb[4];
    #pragma unroll
    for (int f = 0; f < 4; f++) {
      a[f]  = *(const bf16x8*)(ob + (size_t)(R0 + f * 16 + ra) * DD + ks * 32 + kg);
      bb[f] = *(const bf16x8*)(ob + (size_t)(C0 + f * 16 + ra) * DD + ks * 32 + kg);
    }
    #pragma unroll
    for (int fi = 0; fi < 4; fi++)
      #pragma unroll
      for (int fj = 0; fj < 4; fj++)
        acc[fi][fj] = __builtin_amdgcn_mfma_f32_16x16x32_bf16(a[fi], bb[fj], acc[fi][fj], 0, 0, 0);
  }
  #pragma unroll
  for (int fi = 0; fi < 4; fi++) {
    int rbase = R0 + fi * 16 + (lane >> 4) * 4;
    #pragma unroll
    for (int reg = 0; reg < 4; reg++) {
      float* Crow = C + (size_t)(rbase + reg) * NN + (lane & 15);
      #pragma unroll
      for (int fj = 0; fj < 4; fj++)
        Crow[C0 + fj * 16] = acc[fi][fj][reg];
    }
  }
}

extern "C" void kernel_launch(void* const* d_in, const int* in_sizes, int n_in,
                              void* d_out, int out_size, void* d_ws, size_t ws_size,
                              hipStream_t stream) {
  const float* x  = (const float*)d_in[0];
  const int*   ei = (const int*)d_in[1];
  const float* W  = (const float*)d_in[2];
  const float* b  = (const float*)d_in[3];
  float* C = (float*)d_out;

  char* base = (char*)d_ws;
  int*   deg  = (int*)base;                                    // 32 KB
  int*   cnt  = (int*)(base + 32 * 1024);                      // 32 KB
  float* dinv = (float*)(base + 64 * 1024);                    // 32 KB
  float* h    = (float*)(base + 96 * 1024);                    // 4 MB
  __hip_bfloat16* obf = (__hip_bfloat16*)(base + 96 * 1024 + 4 * 1024 * 1024); // 2 MB
  int*   bucket = (int*)(base + 96 * 1024 + 6 * 1024 * 1024);  // 4 MB

  k_init   <<<NN / 256, 256, 0, stream>>>(deg, cnt);
  k_scatter<<<EE / 256, 256, 0, stream>>>(ei, deg, cnt, bucket);
  k_dinv   <<<NN / 256, 256, 0, stream>>>(deg, dinv);
  k_linear <<<NN / 16, 256, 0, stream>>>(x, W, h);
  k_medoid <<<NN, 256, 0, stream>>>(cnt, bucket, dinv, h, b, obf);
  k_outer  <<<dim3(64, 64), 256, 0, stream>>>((const short*)obf, C);
}

// Round 4
// 476.756 us; speedup vs baseline: 1.0172x; 1.0172x over previous
//
#include <hip/hip_runtime.h>
#include <hip/hip_bf16.h>
#include <math.h>

#define NN 8192
#define DD 128
#define EE 262144
#define CAPM 128

typedef __attribute__((ext_vector_type(8))) short bf16x8;
typedef __attribute__((ext_vector_type(4))) float f32x4;

// ---------------- init: deg=1 (self loop), cnt=0 (ws is poisoned each call) --
__global__ __launch_bounds__(256) void k_init(int* deg, int* cnt) {
  int i = blockIdx.x * 256 + threadIdx.x;
  if (i < NN) { deg[i] = 1; cnt[i] = 0; }
}

// ---------------- scatter edges: degree count + per-row col buckets ---------
__global__ __launch_bounds__(256) void k_scatter(const int* __restrict__ ei,
                                                 int* deg, int* cnt, int* bucket) {
  int e = blockIdx.x * 256 + threadIdx.x;
  if (e < EE) {
    int r = ei[e];
    int c = ei[EE + e];
    atomicAdd(&deg[c], 1);
    int pos = atomicAdd(&cnt[r], 1);
    if (pos < CAPM - 1) bucket[r * CAPM + pos] = c;   // reserve last slot for self-loop
  }
}

__global__ __launch_bounds__(256) void k_dinv(const int* __restrict__ deg, float* dinv) {
  int i = blockIdx.x * 256 + threadIdx.x;
  if (i < NN) dinv[i] = 1.0f / sqrtf((float)deg[i]);
}

// ---------------- h = x @ W (fp32, W rows L2-resident) ----------------------
__global__ __launch_bounds__(256) void k_linear(const float* __restrict__ x,
                                                const float* __restrict__ W,
                                                float* __restrict__ h) {
  __shared__ float xr[2][DD];
  int j = threadIdx.x & 127, par = threadIdx.x >> 7;
  for (int rr = 0; rr < 16; rr += 2) {
    int row = blockIdx.x * 16 + rr + par;
    __syncthreads();
    xr[par][j] = x[row * DD + j];
    __syncthreads();
    float acc = 0.f;
    #pragma unroll 8
    for (int k = 0; k < DD; k++) acc = fmaf(xr[par][k], W[k * DD + j], acc);
    h[row * DD + j] = acc;
  }
}

// ---------------- per-row soft-k-medoid + bias + relu -> bf16 o -------------
#define XS 132   // LDS row stride (floats): 16B-aligned, bank-staggered
__global__ __launch_bounds__(256) void k_medoid(const int* __restrict__ cnt,
                                                const int* __restrict__ bucket,
                                                const float* __restrict__ dinv,
                                                const float* __restrict__ h,
                                                const float* __restrict__ bias,
                                                __hip_bfloat16* __restrict__ obf) {
  __shared__ int   sc[CAPM];
  __shared__ float sdv[CAPM];
  __shared__ float uw[CAPM];
  __shared__ int   uc[CAPM];
  __shared__ float Xk[64 * XS];
  __shared__ float sq[64];
  __shared__ float lv[64];
  __shared__ float carr[64];
  __shared__ float red[4];
  __shared__ int   s_wcnt[4];
  __shared__ float s_rs;
  __shared__ int   s_mu;

  const int r = blockIdx.x;
  const int tid = threadIdx.x;
  const int lane = tid & 63, wid = tid >> 6;

  const int cntr = min(cnt[r], CAPM - 1);
  const int m = cntr + 1;                      // + self loop
  for (int p = tid; p < cntr; p += 256) sc[p] = bucket[r * CAPM + p];
  if (tid == 0) sc[cntr] = r;
  __syncthreads();
  const float dr = dinv[r];
  for (int p = tid; p < m; p += 256) sdv[p] = dinv[sc[p]];
  __syncthreads();

  // dedup: head flag + multiplicity (coalesce duplicate edges); O(m) per entry
  bool head = false; int mult = 0; int c = -1; float dvp = 0.f;
  if (tid < m) {
    c = sc[tid]; dvp = sdv[tid];
    head = true;
    for (int q = 0; q < m; q++) {
      int cq = sc[q];
      if (cq == c) { mult++; if (q < tid) head = false; }
    }
  }

  // row_sum = dr * sum over ALL entries (incl. duplicates)
  float rpart = (tid < m) ? dvp : 0.f;
  for (int o = 32; o; o >>= 1) rpart += __shfl_xor(rpart, o);
  if (lane == 0) red[wid] = rpart;
  __syncthreads();
  if (tid == 0) s_rs = dr * (red[0] + red[1] + red[2] + red[3]);

  // compact heads -> unique (col, weight) list
  unsigned long long bal = __ballot(head);
  int rank = __popcll(bal & ((1ULL << lane) - 1ULL));
  if (lane == 0) s_wcnt[wid] = __popcll(bal);
  __syncthreads();
  int ubase = 0;
  for (int wq = 0; wq < wid; wq++) ubase += s_wcnt[wq];
  if (head) { int u = ubase + rank; uc[u] = c; uw[u] = (float)mult * dr * dvp; }
  if (tid == 0) s_mu = s_wcnt[0] + s_wcnt[1] + s_wcnt[2] + s_wcnt[3];
  __syncthreads();
  const int mu = s_mu;
  const float rs = s_rs;

  // rare path: >64 distinct neighbors -> bitonic sort desc by (w, col asc), keep 64
  if (mu > 64) {
    for (int p = tid; p < CAPM; p += 256)
      if (p >= mu) { uw[p] = -1.f; uc[p] = 0x7fffffff; }
    __syncthreads();
    for (int kk = 2; kk <= CAPM; kk <<= 1) {
      for (int jj = kk >> 1; jj > 0; jj >>= 1) {
        if (tid < CAPM) {
          int ixj = tid ^ jj;
          if (ixj > tid) {
            float w1 = uw[tid], w2 = uw[ixj];
            int   c1 = uc[tid], c2 = uc[ixj];
            bool firstBefore = (w1 > w2) || (w1 == w2 && c1 < c2);
            bool up = ((tid & kk) == 0);
            bool sw = up ? !firstBefore : firstBefore;
            if (sw) { uw[tid] = w2; uw[ixj] = w1; uc[tid] = c2; uc[ixj] = c1; }
          }
        }
        __syncthreads();
      }
    }
  }
  __syncthreads();
  const int K = min(mu, 64);

  // gather neighborhood vectors h[uc[u]] into LDS; zero lv for atomic accum
  if (tid < 64) lv[tid] = 0.f;
  for (int t = tid; t < K * 32; t += 256) {
    int u = t >> 5, d4 = t & 31;
    float4 v = *(const float4*)(h + (size_t)uc[u] * DD + d4 * 4);
    *(float4*)(Xk + u * XS + d4 * 4) = v;
  }
  __syncthreads();

  // squared norms
  {
    int u = tid >> 2, sub = tid & 3;
    if (u < 64) {
      float acc = 0.f;
      if (u < K) {
        for (int d4 = sub; d4 < 32; d4 += 4) {
          float4 v = *(const float4*)(Xk + u * XS + d4 * 4);
          acc += v.x * v.x + v.y * v.y + v.z * v.z + v.w * v.w;
        }
      }
      acc += __shfl_xor(acc, 1);
      acc += __shfl_xor(acc, 2);
      if (sub == 0 && u < K) sq[u] = acc;
    }
  }
  __syncthreads();

  // pairwise phase: 4x4 register-tiled Gram over upper-triangle tiles.
  // l_j = sum_m w_m * dist(j,m); symmetric dist -> each (j<m) pair feeds both
  // lv[j] += w_m*dist and lv[m] += w_j*dist. Diagonal term included once
  // (dist(j,j) = sqrt(max(2(sq_j - dot_jj),1e-12)), same as reference).
  {
    const int ntile = (K + 3) >> 2;
    const int T = ntile * (ntile + 1) / 2;
    if (tid < T) {
      int p = tid, ti = 0;
      while (p >= ntile - ti) { p -= ntile - ti; ti++; }
      int tj = ti + p;
      const int j0 = ti * 4, m0 = tj * 4;
      float dd[4][4];
      #pragma unroll
      for (int i = 0; i < 4; i++)
        #pragma unroll
        for (int jj = 0; jj < 4; jj++) dd[i][jj] = 0.f;
      const float* Arow = Xk + j0 * XS;
      const float* Brow = Xk + m0 * XS;
      #pragma unroll 2
      for (int d4 = 0; d4 < 32; d4++) {
        float4 a0 = *(const float4*)(Arow + 0 * XS + d4 * 4);
        float4 a1 = *(const float4*)(Arow + 1 * XS + d4 * 4);
        float4 a2 = *(const float4*)(Arow + 2 * XS + d4 * 4);
        float4 a3 = *(const float4*)(Arow + 3 * XS + d4 * 4);
        float4 b0 = *(const float4*)(Brow + 0 * XS + d4 * 4);
        float4 b1 = *(const float4*)(Brow + 1 * XS + d4 * 4);
        float4 b2 = *(const float4*)(Brow + 2 * XS + d4 * 4);
        float4 b3 = *(const float4*)(Brow + 3 * XS + d4 * 4);
        #pragma unroll
        for (int i = 0; i < 4; i++) {
          float4 a = (i == 0) ? a0 : (i == 1) ? a1 : (i == 2) ? a2 : a3;
          #pragma unroll
          for (int jj = 0; jj < 4; jj++) {
            float4 bq = (jj == 0) ? b0 : (jj == 1) ? b1 : (jj == 2) ? b2 : b3;
            dd[i][jj] = fmaf(a.x, bq.x, fmaf(a.y, bq.y, fmaf(a.z, bq.z, fmaf(a.w, bq.w, dd[i][jj]))));
          }
        }
      }
      float lpJ[4] = {0.f, 0.f, 0.f, 0.f};
      float lpM[4] = {0.f, 0.f, 0.f, 0.f};
      #pragma unroll
      for (int i = 0; i < 4; i++) {
        int j = j0 + i;
        #pragma unroll
        for (int jj = 0; jj < 4; jj++) {
          int mc = m0 + jj;
          if (j < K && mc < K && j <= mc) {
            float d2 = sq[j] + sq[mc] - 2.f * dd[i][jj];
            float dist = sqrtf(fmaxf(d2, 1e-12f));
            if (j == mc) {
              lpJ[i] += uw[j] * dist;
            } else {
              lpJ[i] += uw[mc] * dist;
              lpM[jj] += uw[j] * dist;
            }
          }
        }
      }
      #pragma unroll
      for (int i = 0; i < 4; i++)
        if (lpJ[i] != 0.f) atomicAdd(&lv[j0 + i], lpJ[i]);
      #pragma unroll
      for (int jj = 0; jj < 4; jj++)
        if (lpM[jj] != 0.f) atomicAdd(&lv[m0 + jj], lpM[jj]);
    }
  }
  __syncthreads();

  // softmax(-l/row_sum) * w, normalized, scaled by row_sum (single wave)
  if (tid < 64) {
    float lj = (tid < K) ? lv[tid] : INFINITY;
    float z = -lj / rs;
    float zm = z;
    for (int o = 32; o; o >>= 1) zm = fmaxf(zm, __shfl_xor(zm, o));
    float e = (tid < K) ? expf(z - zm) : 0.f;
    float esum = e;
    for (int o = 32; o; o >>= 1) esum += __shfl_xor(esum, o);
    float s = e / esum;
    float cc = (tid < K) ? s * uw[tid] : 0.f;
    float csum = cc;
    for (int o = 32; o; o >>= 1) csum += __shfl_xor(csum, o);
    carr[tid] = cc / csum * rs;
  }
  __syncthreads();

  // out_row = sum_j c_j * x_j ; + bias ; relu ; store bf16
  if (tid < DD) {
    int d = tid;
    float acc = 0.f;
    for (int j = 0; j < K; j++) acc = fmaf(carr[j], Xk[j * XS + d], acc);
    acc += bias[d];
    acc = fmaxf(acc, 0.f);
    obf[(size_t)r * DD + d] = __float2bfloat16(acc);
  }
}

// ---------------- C = o @ o^T  (bf16 MFMA, K=128, operands L2-resident) -----
__global__ __launch_bounds__(256) void k_outer(const short* __restrict__ ob,
                                               float* __restrict__ C) {
  const int lane = threadIdx.x & 63, w = threadIdx.x >> 6;
  const int R0 = blockIdx.x * 128 + (w >> 1) * 64;
  const int C0 = blockIdx.y * 128 + (w & 1) * 64;
  const int ra = lane & 15;
  const int kg = (lane >> 4) * 8;

  f32x4 acc[4][4] = {};
  #pragma unroll
  for (int ks = 0; ks < 4; ks++) {
    bf16x8 a[4], bb[4];
    #pragma unroll
    for (int f = 0; f < 4; f++) {
      a[f]  = *(const bf16x8*)(ob + (size_t)(R0 + f * 16 + ra) * DD + ks * 32 + kg);
      bb[f] = *(const bf16x8*)(ob + (size_t)(C0 + f * 16 + ra) * DD + ks * 32 + kg);
    }
    #pragma unroll
    for (int fi = 0; fi < 4; fi++)
      #pragma unroll
      for (int fj = 0; fj < 4; fj++)
        acc[fi][fj] = __builtin_amdgcn_mfma_f32_16x16x32_bf16(a[fi], bb[fj], acc[fi][fj], 0, 0, 0);
  }
  #pragma unroll
  for (int fi = 0; fi < 4; fi++) {
    int rbase = R0 + fi * 16 + (lane >> 4) * 4;
    #pragma unroll
    for (int reg = 0; reg < 4; reg++) {
      float* Crow = C + (size_t)(rbase + reg) * NN + (lane & 15);
      #pragma unroll
      for (int fj = 0; fj < 4; fj++)
        Crow[C0 + fj * 16] = acc[fi][fj][reg];
    }
  }
}

extern "C" void kernel_launch(void* const* d_in, const int* in_sizes, int n_in,
                              void* d_out, int out_size, void* d_ws, size_t ws_size,
                              hipStream_t stream) {
  const float* x  = (const float*)d_in[0];
  const int*   ei = (const int*)d_in[1];
  const float* W  = (const float*)d_in[2];
  const float* b  = (const float*)d_in[3];
  float* C = (float*)d_out;

  char* base = (char*)d_ws;
  int*   deg  = (int*)base;                                    // 32 KB
  int*   cnt  = (int*)(base + 32 * 1024);                      // 32 KB
  float* dinv = (float*)(base + 64 * 1024);                    // 32 KB
  float* h    = (float*)(base + 96 * 1024);                    // 4 MB
  __hip_bfloat16* obf = (__hip_bfloat16*)(base + 96 * 1024 + 4 * 1024 * 1024); // 2 MB
  int*   bucket = (int*)(base + 96 * 1024 + 6 * 1024 * 1024);  // 4 MB

  k_init   <<<NN / 256, 256, 0, stream>>>(deg, cnt);
  k_scatter<<<EE / 256, 256, 0, stream>>>(ei, deg, cnt, bucket);
  k_dinv   <<<NN / 256, 256, 0, stream>>>(deg, dinv);
  k_linear <<<NN / 16, 256, 0, stream>>>(x, W, h);
  k_medoid <<<NN, 256, 0, stream>>>(cnt, bucket, dinv, h, b, obf);
  k_outer  <<<dim3(64, 64), 256, 0, stream>>>((const short*)obf, C);
}